// Round 7
// baseline (31.764 us; speedup 1.0000x reference)
//
#include <hip/hip_runtime.h>

#define HH 224
#define WW 224
#define K 15
#define PAD 7
#define BX 32
#define BY 8
#define VO 2                         /* vertical outputs per thread */
#define OROWS (BY * VO)              /* 16 output rows per block */
#define TROWS (OROWS + K - 1)        /* 30 staged rows */
#define TW (BX + K - 1)              /* 46 staged cols */
#define TSTRIDE 48                   /* bank shift 16/row -> 2-way (free) */

__global__ __launch_bounds__(BX * BY)
void bilateral_denoise_kernel(const float* __restrict__ x,
                              const float* __restrict__ blur_sigma_p,
                              const float* __restrict__ diff_sigma_p,
                              float* __restrict__ out)
{
    __shared__ float tile[TROWS * TSTRIDE];

    const int tx = threadIdx.x;        // 0..31
    const int ty = threadIdx.y;        // 0..7
    const int w0 = blockIdx.x * BX;
    const int h0 = blockIdx.y * OROWS;
    const int plane = blockIdx.z;      // b*C + c, 0..5

    const float* __restrict__ xp = x + (size_t)plane * HH * WW;

    // ---- stage 30x46 halo tile (boundary -> -100) ----
    for (int rr = ty; rr < TROWS; rr += BY) {
        const int gh = h0 - PAD + rr;
        for (int cc = tx; cc < TW; cc += BX) {
            const int gw = w0 - PAD + cc;
            float v = -100.0f;
            if (gh >= 0 && gh < HH && gw >= 0 && gw < WW) v = xp[gh * WW + gw];
            tile[rr * TSTRIDE + cc] = v;
        }
    }
    __syncthreads();

    const float bs = blur_sigma_p[0];
    const float ds = diff_sigma_p[0];
    const float LOG2E = 1.44269504088896340736f;
    const float na  = -LOG2E / (ds * ds);
    const float nk2 = -LOG2E / (bs * bs);

    const int r0 = 2 * ty;             // A-window base tile row
    const float cvA = tile[(r0 + PAD)     * TSTRIDE + tx + PAD];
    const float cvB = tile[(r0 + PAD + 1) * TSTRIDE + tx + PAD];
    const float bbA = -2.0f * na * cvA;
    const float ccA = na * cvA * cvA;
    const float bbB = -2.0f * na * cvB;
    const float ccB = na * cvB * cvB;

    float awA[K], avA[K], awB[K], avB[K];
#pragma unroll
    for (int j = 0; j < K; ++j) { awA[j] = 0.0f; avA[j] = 0.0f; awB[j] = 0.0f; avB[j] = 0.0f; }

    // union of the two windows: 16 rows; middle 14 feed both outputs.
    // one ds_read feeds up to 2 taps -> reads/output = 240/2 = 120 (was 225).
#pragma unroll
    for (int r = 0; r < 16; ++r) {
        const float* __restrict__ row = &tile[(r0 + r) * TSTRIDE + tx];
        float rv[K];
#pragma unroll
        for (int j = 0; j < K; ++j) rv[j] = row[j];

        if (r < 15) {                  // compile-time: row feeds output A
            const int iA = r;
            const float ciA = __builtin_fmaf((float)((iA - PAD) * (iA - PAD)), nk2, ccA);
#pragma unroll
            for (int j = 0; j < K; ++j) {
                const float v = rv[j];
                const float inner = __builtin_fmaf(v, na, bbA);
                const float t = __builtin_fmaf(v, inner, ciA);
                const float e = __builtin_amdgcn_exp2f(t);
                awA[j] += e;
                avA[j] = __builtin_fmaf(e, v, avA[j]);
            }
        }
        if (r >= 1) {                  // compile-time: row feeds output B
            const int iB = r - 1;
            const float ciB = __builtin_fmaf((float)((iB - PAD) * (iB - PAD)), nk2, ccB);
#pragma unroll
            for (int j = 0; j < K; ++j) {
                const float v = rv[j];
                const float inner = __builtin_fmaf(v, na, bbB);
                const float t = __builtin_fmaf(v, inner, ciB);
                const float e = __builtin_amdgcn_exp2f(t);
                awB[j] += e;
                avB[j] = __builtin_fmaf(e, v, avB[j]);
            }
        }
    }

    // finale: fold column spatial weights
    float wA = 0.0f, vA = 0.0f, wB = 0.0f, vB = 0.0f;
#pragma unroll
    for (int j = 0; j < K; ++j) {
        const float wj = __builtin_amdgcn_exp2f((float)((j - PAD) * (j - PAD)) * nk2);
        wA = __builtin_fmaf(wj, awA[j], wA);
        vA = __builtin_fmaf(wj, avA[j], vA);
        wB = __builtin_fmaf(wj, awB[j], wB);
        vB = __builtin_fmaf(wj, avB[j], vB);
    }

    const size_t base = (size_t)plane * HH * WW + (size_t)(h0 + 2 * ty) * WW + (w0 + tx);
    out[base]      = vA / wA;
    out[base + WW] = vB / wB;
}

extern "C" void kernel_launch(void* const* d_in, const int* in_sizes, int n_in,
                              void* d_out, int out_size, void* d_ws, size_t ws_size,
                              hipStream_t stream) {
    const float* x  = (const float*)d_in[0];
    const float* bs = (const float*)d_in[1];
    const float* ds = (const float*)d_in[2];
    float* out = (float*)d_out;

    const int planes = in_sizes[0] / (HH * WW);     // B*C = 6
    dim3 grid(WW / BX, HH / OROWS, planes);         // 7 x 14 x 6 = 588 blocks
    dim3 block(BX, BY, 1);
    hipLaunchKernelGGL(bilateral_denoise_kernel, grid, block, 0, stream,
                       x, bs, ds, out);
}

// Round 8
// 25.703 us; speedup vs baseline: 1.2358x; 1.2358x over previous
//
#include <hip/hip_runtime.h>

#define HH 224
#define WW 224
#define K 15
#define PAD 7
#define PH (HH + 2 * PAD)     /* 238 padded rows */
#define PSTRIDE 240           /* padded row stride in floats (960 B) */
#define NPLANES 6
#define BX 32
#define BY 8

/* ---- kernel 1: pad x (+border -100) into d_ws, fully rewritten every call ---- */
__global__ __launch_bounds__(256)
void pad_kernel(const float* __restrict__ x, float* __restrict__ xpad)
{
    const int idx = blockIdx.x * 256 + threadIdx.x;
    const int total = NPLANES * PH * PSTRIDE;
    if (idx >= total) return;
    const int p   = idx / (PH * PSTRIDE);
    const int rem = idx - p * (PH * PSTRIDE);
    const int r   = rem / PSTRIDE;
    const int c   = rem - r * PSTRIDE;
    const int gh = r - PAD;
    const int gw = c - PAD;
    float v = -100.0f;
    if (gh >= 0 && gh < HH && gw >= 0 && gw < WW)
        v = x[(size_t)p * HH * WW + gh * WW + gw];
    xpad[idx] = v;
}

/* ---- kernel 2: R2 tap structure, taps read via VMEM (L1/L2), zero LDS ---- */
__global__ __launch_bounds__(BX * BY)
void bilateral_denoise_kernel(const float* __restrict__ xpad,
                              const float* __restrict__ blur_sigma_p,
                              const float* __restrict__ diff_sigma_p,
                              float* __restrict__ out)
{
    const int tx = threadIdx.x;             // 0..31
    const int ty = threadIdx.y;             // 0..7
    const int w0 = blockIdx.x * BX;
    const int h  = blockIdx.y * BY + ty;    // output row
    const int plane = blockIdx.z;           // 0..5

    // padded coords: original (h,w) lives at padded (h+PAD, w+PAD);
    // tap (i,j) of output (h,w) = xpad[h+i][w+j] in padded coords.
    const float* __restrict__ base =
        xpad + (size_t)plane * PH * PSTRIDE + (size_t)h * PSTRIDE + (w0 + tx);

    const float bs = blur_sigma_p[0];
    const float ds = diff_sigma_p[0];
    const float LOG2E = 1.44269504088896340736f;
    const float na  = -LOG2E / (ds * ds);
    const float nk2 = -LOG2E / (bs * bs);

    const float cv = base[PAD * PSTRIDE + PAD];
    // na*(v-cv)^2 = na*v^2 + bb*v + cc2
    const float bb  = -2.0f * na * cv;
    const float cc2 = na * cv * cv;

    float colw[K];
    float colv[K];
#pragma unroll
    for (int j = 0; j < K; ++j) { colw[j] = 0.0f; colv[j] = 0.0f; }

#pragma unroll
    for (int i = 0; i < K; ++i) {
        const float ci = __builtin_fmaf((float)((i - PAD) * (i - PAD)), nk2, cc2);
        const float* __restrict__ row = base + i * PSTRIDE;
#pragma unroll
        for (int j = 0; j < K; ++j) {
            const float v = row[j];                           // global_load (L1-hit)
            const float inner = __builtin_fmaf(v, na, bb);    // na*v + bb
            const float t = __builtin_fmaf(v, inner, ci);     // na*v^2 + bb*v + ci
            const float e = __builtin_amdgcn_exp2f(t);
            colw[j] += e;
            colv[j] = __builtin_fmaf(e, v, colv[j]);
        }
    }

    float wsum = 0.0f;
    float vsum = 0.0f;
#pragma unroll
    for (int j = 0; j < K; ++j) {
        const float wj = __builtin_amdgcn_exp2f((float)((j - PAD) * (j - PAD)) * nk2);
        wsum = __builtin_fmaf(wj, colw[j], wsum);
        vsum = __builtin_fmaf(wj, colv[j], vsum);
    }

    out[(size_t)plane * HH * WW + (size_t)h * WW + (w0 + tx)] = vsum / wsum;
}

extern "C" void kernel_launch(void* const* d_in, const int* in_sizes, int n_in,
                              void* d_out, int out_size, void* d_ws, size_t ws_size,
                              hipStream_t stream) {
    const float* x  = (const float*)d_in[0];
    const float* bs = (const float*)d_in[1];
    const float* ds = (const float*)d_in[2];
    float* out  = (float*)d_out;
    float* xpad = (float*)d_ws;     // needs 6*238*240*4 = 1,370,880 B of scratch

    const int total = NPLANES * PH * PSTRIDE;
    hipLaunchKernelGGL(pad_kernel, dim3((total + 255) / 256), dim3(256), 0, stream,
                       x, xpad);

    dim3 grid(WW / BX, HH / BY, NPLANES);   // 7 x 28 x 6 = 1176 blocks
    dim3 block(BX, BY, 1);
    hipLaunchKernelGGL(bilateral_denoise_kernel, grid, block, 0, stream,
                       xpad, bs, ds, out);
}

// Round 9
// 24.278 us; speedup vs baseline: 1.3083x; 1.0587x over previous
//
#include <hip/hip_runtime.h>

#define HH 224
#define WW 224
#define K 15
#define PAD 7
#define BX 32
#define BY 8
#define TW (BX + K - 1)   /* 46 */
#define TH (BY + K - 1)   /* 22 */
#define TSTRIDE 48        /* row-to-row bank shift = 16 -> 2-way aliasing (free) */

/* exp2 in full-rate VALU: n=rint(t), f=t-n, 2^f Taylor deg-3, scale by 2^n.
   rel err <= ~6e-4 on f in [-0.5,0.5]; ldexp underflow -> exact 0 for pad taps. */
__device__ __forceinline__ float exp2_poly(float t)
{
    const float fn = __builtin_rintf(t);        // v_rndne_f32
    const int   ni = (int)fn;                   // exact (fn integer-valued)
    const float f  = t - fn;                    // [-0.5, 0.5]
    float p = __builtin_fmaf(f, 0.05550411f, 0.24022651f);
    p = __builtin_fmaf(f, p, 0.69314718f);
    p = __builtin_fmaf(f, p, 1.0f);
    return __builtin_ldexpf(p, ni);             // v_ldexp_f32
}

__global__ __launch_bounds__(BX * BY)
void bilateral_denoise_kernel(const float* __restrict__ x,
                              const float* __restrict__ blur_sigma_p,
                              const float* __restrict__ diff_sigma_p,
                              float* __restrict__ out)
{
    __shared__ float tile[TH * TSTRIDE];

    const int tx = threadIdx.x;           // 0..31
    const int ty = threadIdx.y;           // 0..7
    const int tid = ty * BX + tx;
    const int w0 = blockIdx.x * BX;
    const int h0 = blockIdx.y * BY;
    const int plane = blockIdx.z;         // b*C + c, 0..5

    const float* __restrict__ xp = x + (size_t)plane * HH * WW;

    // ---- stage halo tile (boundary -> -100, matching constant pad) ----
    for (int idx = tid; idx < TH * TW; idx += BX * BY) {
        const int r = idx / TW;
        const int c = idx - r * TW;
        const int gh = h0 - PAD + r;
        const int gw = w0 - PAD + c;
        float v = -100.0f;
        if (gh >= 0 && gh < HH && gw >= 0 && gw < WW) v = xp[gh * WW + gw];
        tile[r * TSTRIDE + c] = v;
    }
    __syncthreads();

    const float bs = blur_sigma_p[0];
    const float ds = diff_sigma_p[0];
    const float LOG2E = 1.44269504088896340736f;
    const float na  = -LOG2E / (ds * ds);   // scale on (v-cv)^2
    const float nk2 = -LOG2E / (bs * bs);   // scale on spatial squared distance

    const float cv = tile[(ty + PAD) * TSTRIDE + tx + PAD];
    // na*(v-cv)^2 = na*v^2 + bb*v + cc
    const float bb = -2.0f * na * cv;
    const float cc = na * cv * cv;

    float colw[K];
    float colv[K];
#pragma unroll
    for (int j = 0; j < K; ++j) { colw[j] = 0.0f; colv[j] = 0.0f; }

#pragma unroll
    for (int i = 0; i < K; ++i) {
        const float ci = __builtin_fmaf((float)((i - PAD) * (i - PAD)), nk2, cc);
        const float* __restrict__ row = &tile[(ty + i) * TSTRIDE + tx];
#pragma unroll
        for (int j = 0; j < K; ++j) {
            const float v = row[j];
            const float inner = __builtin_fmaf(v, na, bb);     // na*v + bb
            const float t = __builtin_fmaf(v, inner, ci);      // na*v^2 + bb*v + ci
            const float e = exp2_poly(t);                      // all-VALU, no trans op
            colw[j] += e;
            colv[j] = __builtin_fmaf(e, v, colv[j]);
        }
    }

    float wsum = 0.0f;
    float vsum = 0.0f;
#pragma unroll
    for (int j = 0; j < K; ++j) {
        const float wj = __builtin_amdgcn_exp2f((float)((j - PAD) * (j - PAD)) * nk2);
        wsum = __builtin_fmaf(wj, colw[j], wsum);
        vsum = __builtin_fmaf(wj, colv[j], vsum);
    }

    out[(size_t)plane * HH * WW + (size_t)(h0 + ty) * WW + (w0 + tx)] = vsum / wsum;
}

extern "C" void kernel_launch(void* const* d_in, const int* in_sizes, int n_in,
                              void* d_out, int out_size, void* d_ws, size_t ws_size,
                              hipStream_t stream) {
    const float* x  = (const float*)d_in[0];
    const float* bs = (const float*)d_in[1];
    const float* ds = (const float*)d_in[2];
    float* out = (float*)d_out;

    const int planes = in_sizes[0] / (HH * WW);   // B*C = 6
    dim3 grid(WW / BX, HH / BY, planes);          // 7 x 28 x 6 = 1176 blocks
    dim3 block(BX, BY, 1);
    hipLaunchKernelGGL(bilateral_denoise_kernel, grid, block, 0, stream,
                       x, bs, ds, out);
}